// Round 4
// baseline (329.636 us; speedup 1.0000x reference)
//
#include <hip/hip_runtime.h>
#include <hip/hip_bf16.h>
#include <cstdint>

typedef __attribute__((ext_vector_type(8))) short short8;
typedef __attribute__((ext_vector_type(4))) short short4_t;
typedef __attribute__((ext_vector_type(4))) float f32x4;

#define MFMA16(a, b, c) __builtin_amdgcn_mfma_f32_16x16x32_bf16(a, b, c, 0, 0, 0)

__device__ __forceinline__ short f2b(float f) {
    union { float fp; unsigned u; } un; un.fp = f;
    unsigned r = un.u + 0x7fffu + ((un.u >> 16) & 1u);
    return (short)(r >> 16);
}

#if __has_builtin(__builtin_amdgcn_cvt_pk_bf16_f32)
__device__ __forceinline__ unsigned pk_bf16(float a, float b) {
    auto r = __builtin_amdgcn_cvt_pk_bf16_f32(a, b);
    unsigned u; __builtin_memcpy(&u, &r, 4); return u;
}
#else
__device__ __forceinline__ unsigned pk_bf16(float a, float b) {
    return (unsigned)(unsigned short)f2b(a) | ((unsigned)(unsigned short)f2b(b) << 16);
}
#endif

union pk8_u { unsigned u4[4]; short8 s8; };
union cat8_u { short4_t s4[2]; short8 s8; };

typedef const __attribute__((address_space(1))) unsigned g_as1;
typedef __attribute__((address_space(3))) unsigned l_as3;
__device__ __forceinline__ void gll16(const ushort* g, ushort* l) {
    __builtin_amdgcn_global_load_lds((g_as1*)g, (l_as3*)l, 16, 0, 0);
}

// ---------------------------------------------------------------------------
// fp32 -> bf16 convert of query / context
// ---------------------------------------------------------------------------
__global__ __launch_bounds__(256) void in_cvt_kernel(
    const float* __restrict__ q, const float* __restrict__ c,
    ushort* __restrict__ qb, ushort* __restrict__ cb)
{
    const float* src = blockIdx.y ? c : q;
    ushort* dst = blockIdx.y ? cb : qb;
    size_t i = ((size_t)blockIdx.x * 256 + threadIdx.x) * 8;
    float4 v0 = *(const float4*)&src[i];
    float4 v1 = *(const float4*)&src[i + 4];
    uint4 o;
    o.x = pk_bf16(v0.x, v0.y); o.y = pk_bf16(v0.z, v0.w);
    o.z = pk_bf16(v1.x, v1.y); o.w = pk_bf16(v1.z, v1.w);
    *(uint4*)&dst[i] = o;
}

// ---------------------------------------------------------------------------
// Weight transpose+convert: fp32 [k][n] -> bf16 [n][k]
// ---------------------------------------------------------------------------
__global__ __launch_bounds__(256) void wt_cvt_kernel(
    const float* __restrict__ Wq, const float* __restrict__ Wk,
    const float* __restrict__ Wv, const float* __restrict__ Wo,
    ushort* __restrict__ wt)
{
    __shared__ float Ts[64 * 65];
    const int z = blockIdx.z;
    const float* W = (z == 0) ? Wq : (z == 1) ? Wk : (z == 2) ? Wv : Wo;
    ushort* WT = wt + (size_t)z * (1024 * 1024);
    const int n0 = blockIdx.x * 64, k0 = blockIdx.y * 64;
    const int tid = threadIdx.x;

#pragma unroll
    for (int rr = 0; rr < 4; ++rr) {
        int u = tid + rr * 256;
        int r = u >> 4, c = (u & 15) * 4;
        float4 v = *(const float4*)&W[(size_t)(k0 + r) * 1024 + n0 + c];
        Ts[r * 65 + c + 0] = v.x; Ts[r * 65 + c + 1] = v.y;
        Ts[r * 65 + c + 2] = v.z; Ts[r * 65 + c + 3] = v.w;
    }
    __syncthreads();
#pragma unroll
    for (int rr = 0; rr < 4; ++rr) {
        int u = tid + rr * 256;
        int rn = u >> 4, ck = (u & 15) * 4;
        short4_t o;
        o[0] = f2b(Ts[(ck + 0) * 65 + rn]);
        o[1] = f2b(Ts[(ck + 1) * 65 + rn]);
        o[2] = f2b(Ts[(ck + 2) * 65 + rn]);
        o[3] = f2b(Ts[(ck + 3) * 65 + rn]);
        *(short4_t*)&WT[(size_t)(n0 + rn) * 1024 + k0 + ck] = o;
    }
}

// ---------------------------------------------------------------------------
// GEMM (R2-proven): grid (8 n-tiles, 64 m-tiles), x-fastest.
// MODE 0: out bf16 [b,h,t,d] scaled  (Q projection)
// MODE 3: out fp32 row-major [m][n]  (output projection)
// ---------------------------------------------------------------------------
template <int MODE>
__global__ __launch_bounds__(256) void gemm_kernel(
    const ushort* __restrict__ Ag, const ushort* __restrict__ BT,
    const float* __restrict__ bias, void* __restrict__ Outp, float scale)
{
    __shared__ ushort As[128 * 64];
    __shared__ ushort Bs[128 * 64];
    const int tid = threadIdx.x;
    const int w = tid >> 6, lane = tid & 63;
    const int ln = tid & 15, quad = (tid >> 4) & 3;
    const int wm = w >> 1, wn = w & 1;
    const int m0 = blockIdx.y * 128, n0 = blockIdx.x * 128;

    int offA[4], offB[4], lseg[4];
#pragma unroll
    for (int rr = 0; rr < 4; ++rr) {
        int idx = (rr * 4 + w) * 64 + lane;
        int r = idx >> 3, cst = idx & 7, csrc = cst ^ (r & 7);
        offA[rr] = (m0 + r) * 1024 + csrc * 8;
        offB[rr] = (n0 + r) * 1024 + csrc * 8;
        lseg[rr] = (rr * 4 + w) * 512;
    }

    f32x4 acc[4][4] = {};

    for (int kk = 0; kk < 1024; kk += 64) {
        __syncthreads();
#pragma unroll
        for (int rr = 0; rr < 4; ++rr)
            gll16(&Ag[(size_t)(offA[rr] + kk)], &As[lseg[rr]]);
#pragma unroll
        for (int rr = 0; rr < 4; ++rr)
            gll16(&BT[(size_t)(offB[rr] + kk)], &Bs[lseg[rr]]);
        __syncthreads();

#pragma unroll
        for (int ks = 0; ks < 2; ++ks) {
            short8 af[4], bfr[4];
#pragma unroll
            for (int i = 0; i < 4; ++i)
                af[i] = *(const short8*)&As[(wm * 64 + i * 16 + ln) * 64 +
                                            ((ks * 4 + quad) ^ (ln & 7)) * 8];
#pragma unroll
            for (int j = 0; j < 4; ++j)
                bfr[j] = *(const short8*)&Bs[(wn * 64 + j * 16 + ln) * 64 +
                                             ((ks * 4 + quad) ^ (ln & 7)) * 8];
#pragma unroll
            for (int i = 0; i < 4; ++i)
#pragma unroll
                for (int j = 0; j < 4; ++j)
                    acc[i][j] = MFMA16(af[i], bfr[j], acc[i][j]);
        }
    }

#pragma unroll
    for (int j = 0; j < 4; ++j) {
        int n = n0 + wn * 64 + j * 16 + ln;
        float bv = bias[n];
#pragma unroll
        for (int i = 0; i < 4; ++i) {
            int mb = m0 + wm * 64 + i * 16 + quad * 4;
            if (MODE == 3) {
                float* Out = (float*)Outp;
#pragma unroll
                for (int r = 0; r < 4; ++r)
                    Out[(size_t)(mb + r) * 1024 + n] = acc[i][j][r] + bv;
            } else {
                ushort* Out = (ushort*)Outp;
                int h = n >> 6, d = n & 63;
#pragma unroll
                for (int r = 0; r < 4; ++r) {
                    int m = mb + r, b = m >> 11, t = m & 2047;
                    Out[(((size_t)(b * 16 + h) * 2048 + t) << 6) + d] =
                        (ushort)f2b((acc[i][j][r] + bv) * scale);
                }
            }
        }
    }
}

// ---------------------------------------------------------------------------
// Fused K+V projection (unchanged from R5). grid (16, 64), x-fastest.
// ---------------------------------------------------------------------------
__global__ __launch_bounds__(256) void kv_kernel(
    const ushort* __restrict__ Cb, const ushort* __restrict__ WTk,
    const ushort* __restrict__ WTv,
    const float* __restrict__ bk, const float* __restrict__ bv,
    ushort* __restrict__ Kw, ushort* __restrict__ Vtw)
{
    __shared__ ushort As[128 * 64];
    __shared__ ushort Bs[128 * 64];
    const int tid = threadIdx.x;
    const int w = tid >> 6, lane = tid & 63;
    const int ln = tid & 15, quad = (tid >> 4) & 3;
    const int wm = w >> 1, wn = w & 1;
    const int z = blockIdx.x >> 3;
    const int n0 = (blockIdx.x & 7) * 128;
    const int m0 = blockIdx.y * 128;
    const ushort* BT = z ? WTv : WTk;

    int offA[4], offB[4], lseg[4];
#pragma unroll
    for (int rr = 0; rr < 4; ++rr) {
        int idx = (rr * 4 + w) * 64 + lane;
        int r = idx >> 3, cst = idx & 7, csrc = cst ^ (r & 7);
        offA[rr] = (m0 + r) * 1024 + csrc * 8;
        offB[rr] = (n0 + r) * 1024 + csrc * 8;
        lseg[rr] = (rr * 4 + w) * 512;
    }

    f32x4 acc[4][4] = {};

    for (int kk = 0; kk < 1024; kk += 64) {
        __syncthreads();
#pragma unroll
        for (int rr = 0; rr < 4; ++rr)
            gll16(&Cb[(size_t)(offA[rr] + kk)], &As[lseg[rr]]);
#pragma unroll
        for (int rr = 0; rr < 4; ++rr)
            gll16(&BT[(size_t)(offB[rr] + kk)], &Bs[lseg[rr]]);
        __syncthreads();

#pragma unroll
        for (int ks = 0; ks < 2; ++ks) {
            short8 af[4], bfr[4];
#pragma unroll
            for (int i = 0; i < 4; ++i)
                af[i] = *(const short8*)&As[(wm * 64 + i * 16 + ln) * 64 +
                                            ((ks * 4 + quad) ^ (ln & 7)) * 8];
#pragma unroll
            for (int j = 0; j < 4; ++j)
                bfr[j] = *(const short8*)&Bs[(wn * 64 + j * 16 + ln) * 64 +
                                             ((ks * 4 + quad) ^ (ln & 7)) * 8];
#pragma unroll
            for (int i = 0; i < 4; ++i)
#pragma unroll
                for (int j = 0; j < 4; ++j)
                    acc[i][j] = MFMA16(af[i], bfr[j], acc[i][j]);
        }
    }

#pragma unroll
    for (int j = 0; j < 4; ++j) {
        int n = n0 + wn * 64 + j * 16 + ln;
        int h = n >> 6, d = n & 63;
        if (z == 0) {
            float bvv = bk[n];
#pragma unroll
            for (int i = 0; i < 4; ++i) {
                int mb = m0 + wm * 64 + i * 16 + quad * 4;
#pragma unroll
                for (int r = 0; r < 4; ++r) {
                    int m = mb + r, b = m >> 11, t = m & 2047;
                    Kw[(((size_t)(b * 16 + h) * 2048 + t) << 6) + d] =
                        (ushort)f2b(acc[i][j][r] + bvv);
                }
            }
        } else {
            float bvv = bv[n];
#pragma unroll
            for (int i = 0; i < 4; ++i) {
                int mb = m0 + wm * 64 + i * 16 + quad * 4;
                int b = mb >> 11, t = mb & 2047;
                short4_t o;
                o[0] = f2b(acc[i][j][0] + bvv); o[1] = f2b(acc[i][j][1] + bvv);
                o[2] = f2b(acc[i][j][2] + bvv); o[3] = f2b(acc[i][j][3] + bvv);
                *(short4_t*)&Vtw[(((size_t)((b * 16 + h) * 64 + d)) << 11) + t] = o;
            }
        }
    }
}

// ---------------------------------------------------------------------------
// Flash attention v7: 64 q-rows per wave (4 q-slabs), 2-wave/128-thread
// blocks, q-tile 128 unchanged, grid 1024 + XCD swizzle unchanged.
// R3 accounting: VALU (57% = 55us, mostly per-wave-tile addressing; VGPR=64
// shows compiler recomputes all LDS addrs every tile) and LDS ingest
// (4096 waves x 32 x 16KB = 2.1GB = 40us + 14us conflicts) pace the kernel;
// MFMA busy only 33us. Both costs are per-wave-tile invariants, so halving
// the wave count (2048 waves x 64q) halves them while keeping the MFMA
// total constant (72 K=32 MFMA/wave-tile). VGPR budget opened via
// __launch_bounds__(128,2) -> ~200 VGPR, 2 waves/SIMD; R2 proved extra
// occupancy buys nothing here, and per-wave ILP doubles instead.
// ---------------------------------------------------------------------------
__global__ __launch_bounds__(128, 2) void attn_kernel(
    const ushort* __restrict__ Qw, const ushort* __restrict__ Kw,
    const ushort* __restrict__ Vtw, ushort* __restrict__ attn)
{
    __shared__ ushort Ks[2][4096];      // 64 kv x 64 d, XOR chunk swizzle
    __shared__ ushort Vts[2][4096];     // 64 d  x 64 kv, XOR chunk swizzle

    const int tid = threadIdx.x;        // 0..127
    const int w = tid >> 6, lane = tid & 63;
    const int ln = tid & 15, quad = (tid >> 4) & 3;
    // XCD swizzle (bijective over 1024 = 8*128): xcd = id&7 = bh&7.
    const int id = blockIdx.x;
    const int qt = (id >> 3) & 15;
    const int bh = (id & 7) | ((id >> 7) << 3);
    const int b = bh >> 4, h = bh & 15;

    const ushort* Qg = Qw + (size_t)bh * 131072 + (size_t)qt * 8192;
    const ushort* Kg = Kw + (size_t)bh * 131072;
    const ushort* Vg = Vtw + (size_t)bh * 131072;

    // Q fragments (B-operand of K=32 QK): lane holds Q[q=w*64+qs*16+ln][d]
    short8 bq[4][2];
#pragma unroll
    for (int qs = 0; qs < 4; ++qs)
#pragma unroll
        for (int ks = 0; ks < 2; ++ks)
            bq[qs][ks] = *(const short8*)&Qg[(w * 64 + qs * 16 + ln) * 64 + ks * 32 + quad * 8];

    // staging: 128 threads x 16B = 2KB/round; 4 rounds per 8KB tile.
    int offK[4], offV[4], lseg[4];
#pragma unroll
    for (int rr = 0; rr < 4; ++rr) {
        int idx = (rr * 2 + w) * 64 + lane;
        int r = idx >> 3, cst = idx & 7, csrc = cst ^ (r & 7);
        offK[rr] = r * 64 + csrc * 8;
        offV[rr] = r * 2048 + csrc * 8;
        lseg[rr] = (rr * 2 + w) * 512;
    }

    const short8 ones8 = {(short)0x3F80, (short)0x3F80, (short)0x3F80, (short)0x3F80,
                          (short)0x3F80, (short)0x3F80, (short)0x3F80, (short)0x3F80};

    f32x4 Of[4][4] = {};     // O^T: col = q = ln (qs slab), rows = d-local quad*4+r
    f32x4 lac[4] = {};       // col-sums of P: col = q = ln, rows all equal

    // prologue: stage tile 0 into buffer 0 (drained by the barrier below)
#pragma unroll
    for (int rr = 0; rr < 4; ++rr) gll16(&Kg[offK[rr]], &Ks[0][lseg[rr]]);
#pragma unroll
    for (int rr = 0; rr < 4; ++rr) gll16(&Vg[offV[rr]], &Vts[0][lseg[rr]]);
    __syncthreads();

    auto body = [&](int kt, const ushort* Kc, const ushort* Vc,
                    ushort* Kn, ushort* Vn) {
        // issue next tile's async global->LDS loads FIRST; the end-of-body
        // barrier's vmcnt(0) drain then overlaps this tile's compute.
        if (kt < 31) {
#pragma unroll
            for (int rr = 0; rr < 4; ++rr)
                gll16(&Kg[(kt + 1) * 4096 + offK[rr]], &Kn[lseg[rr]]);
#pragma unroll
            for (int rr = 0; rr < 4; ++rr)
                gll16(&Vg[(kt + 1) * 64 + offV[rr]], &Vn[lseg[rr]]);
        }

        // S^T = K · Q^T (K=32) for kv-block pairs; exp2 + pack into the
        // CONCATENATED K=32 B-operand pf8[qs] (pi-permuted k order).
#pragma unroll
        for (int c = 0; c < 2; ++c) {
            f32x4 s[2][4];
#pragma unroll
            for (int kb = 0; kb < 2; ++kb) {
                int kv = 2 * c + kb;
                short8 a0 = *(const short8*)&Kc[(kv * 16 + ln) * 64 + (quad ^ (ln & 7)) * 8];
                short8 a1 = *(const short8*)&Kc[(kv * 16 + ln) * 64 + ((4 + quad) ^ (ln & 7)) * 8];
#pragma unroll
                for (int qs = 0; qs < 4; ++qs) {
                    f32x4 t = {};
                    t = MFMA16(a0, bq[qs][0], t);
                    t = MFMA16(a1, bq[qs][1], t);
                    s[kb][qs] = t;
                }
            }
            short8 pf8[4];
#pragma unroll
            for (int qs = 0; qs < 4; ++qs) {
                pk8_u pu;
                pu.u4[0] = pk_bf16(__builtin_amdgcn_exp2f(s[0][qs][0]),
                                   __builtin_amdgcn_exp2f(s[0][qs][1]));
                pu.u4[1] = pk_bf16(__builtin_amdgcn_exp2f(s[0][qs][2]),
                                   __builtin_amdgcn_exp2f(s[0][qs][3]));
                pu.u4[2] = pk_bf16(__builtin_amdgcn_exp2f(s[1][qs][0]),
                                   __builtin_amdgcn_exp2f(s[1][qs][1]));
                pu.u4[3] = pk_bf16(__builtin_amdgcn_exp2f(s[1][qs][2]),
                                   __builtin_amdgcn_exp2f(s[1][qs][3]));
                pf8[qs] = pu.s8;
                lac[qs] = MFMA16(ones8, pu.s8, lac[qs]);   // denominator, K=32
            }

            // O^T += V^T · P : K=32, pi-permuted k. A-fragment = two b64
            // reads: j=0..3 -> kv = 32c+quad*4+j ; j=4..7 -> kv+16.
#pragma unroll
            for (int ds = 0; ds < 4; ++ds) {
                const ushort* vrow = &Vc[(ds * 16 + ln) * 64];
                cat8_u av;
                av.s4[0] = *(const short4_t*)&vrow[(((4 * c + (quad >> 1)) ^ (ln & 7)) * 8) + (quad & 1) * 4];
                av.s4[1] = *(const short4_t*)&vrow[(((4 * c + 2 + (quad >> 1)) ^ (ln & 7)) * 8) + (quad & 1) * 4];
#pragma unroll
                for (int qs = 0; qs < 4; ++qs)
                    Of[qs][ds] = MFMA16(av.s8, pf8[qs], Of[qs][ds]);
            }
        }

        // single barrier per tile: drains next-tile vmcnt (overlapped with the
        // compute above) AND guarantees all waves finished reading this buffer.
        __syncthreads();
    };

    for (int kt = 0; kt < 32; kt += 2) {
        body(kt,     Ks[0], Vts[0], Ks[1], Vts[1]);
        body(kt + 1, Ks[1], Vts[1], Ks[0], Vts[0]);
    }

    // finalize: lane ln owns q = w*64 + qs*16 + ln for both l and O columns
#pragma unroll
    for (int qs = 0; qs < 4; ++qs) {
        float inv = __builtin_amdgcn_rcpf(lac[qs][0]);
        int t = qt * 128 + w * 64 + qs * 16 + ln;
        size_t base = ((size_t)(b * 2048 + t) << 10) + h * 64;
#pragma unroll
        for (int ds = 0; ds < 4; ++ds) {
            uint2 o;
            o.x = pk_bf16(Of[qs][ds][0] * inv, Of[qs][ds][1] * inv);
            o.y = pk_bf16(Of[qs][ds][2] * inv, Of[qs][ds][3] * inv);
            *(uint2*)&attn[base + ds * 16 + quad * 4] = o;
        }
    }
}

// ---------------------------------------------------------------------------
extern "C" void kernel_launch(void* const* d_in, const int* in_sizes, int n_in,
                              void* d_out, int out_size, void* d_ws, size_t ws_size,
                              hipStream_t stream)
{
    const float* query   = (const float*)d_in[0];
    const float* context = (const float*)d_in[1];
    const float* Wq = (const float*)d_in[2];
    const float* bq = (const float*)d_in[3];
    const float* Wk = (const float*)d_in[4];
    const float* bk = (const float*)d_in[5];
    const float* Wv = (const float*)d_in[6];
    const float* bv = (const float*)d_in[7];
    const float* Wo = (const float*)d_in[8];
    const float* bo = (const float*)d_in[9];

    char* ws = (char*)d_ws;
    ushort* WT  = (ushort*)ws;                        // 4 x 2 MB bf16 [n][k]
    ushort* Qb  = (ushort*)(ws + 8388608);            // query bf16; later Aw
    ushort* Qw  = (ushort*)(ws + 25165824);           // [b,h,t,d] (pre-scaled)
    ushort* Kw  = (ushort*)(ws + 41943040);           // [b,h,t,d]
    ushort* Vtw = (ushort*)(ws + 58720256);           // [b,h,d,t]
    ushort* Aw  = Qb;                                 // attn out reuses Qb
    ushort* Cb  = (ushort*)d_out;                     // context bf16 in d_out

    const float SCALE = 0.18033688011112042f;         // log2(e)/sqrt(64)

    in_cvt_kernel<<<dim3(4096, 2), 256, 0, stream>>>(query, context, Qb, Cb);
    wt_cvt_kernel<<<dim3(16, 16, 4), 256, 0, stream>>>(Wq, Wk, Wv, Wo, WT);
    gemm_kernel<0><<<dim3(8, 64), 256, 0, stream>>>(Qb, WT + 0 * 1048576, bq, Qw, SCALE);
    kv_kernel<<<dim3(16, 64), 256, 0, stream>>>(Cb, WT + 1 * 1048576,
                                                WT + 2 * 1048576, bk, bv, Kw, Vtw);
    attn_kernel<<<dim3(1024), 128, 0, stream>>>(Qw, Kw, Vtw, Aw);
    gemm_kernel<3><<<dim3(8, 64), 256, 0, stream>>>(Aw, WT + 3 * 1048576, bo,
                                                    (float*)d_out, 1.0f);
}

// Round 5
// 312.611 us; speedup vs baseline: 1.0545x; 1.0545x over previous
//
#include <hip/hip_runtime.h>
#include <hip/hip_bf16.h>
#include <cstdint>

typedef __attribute__((ext_vector_type(8))) short short8;
typedef __attribute__((ext_vector_type(4))) short short4_t;
typedef __attribute__((ext_vector_type(4))) float f32x4;

#define MFMA16(a, b, c) __builtin_amdgcn_mfma_f32_16x16x32_bf16(a, b, c, 0, 0, 0)

__device__ __forceinline__ short f2b(float f) {
    union { float fp; unsigned u; } un; un.fp = f;
    unsigned r = un.u + 0x7fffu + ((un.u >> 16) & 1u);
    return (short)(r >> 16);
}

#if __has_builtin(__builtin_amdgcn_cvt_pk_bf16_f32)
__device__ __forceinline__ unsigned pk_bf16(float a, float b) {
    auto r = __builtin_amdgcn_cvt_pk_bf16_f32(a, b);
    unsigned u; __builtin_memcpy(&u, &r, 4); return u;
}
#else
__device__ __forceinline__ unsigned pk_bf16(float a, float b) {
    return (unsigned)(unsigned short)f2b(a) | ((unsigned)(unsigned short)f2b(b) << 16);
}
#endif

union pk8_u { unsigned u4[4]; short8 s8; };
union cat8_u { short4_t s4[2]; short8 s8; };

typedef const __attribute__((address_space(1))) unsigned g_as1;
typedef __attribute__((address_space(3))) unsigned l_as3;
__device__ __forceinline__ void gll16(const ushort* g, ushort* l) {
    __builtin_amdgcn_global_load_lds((g_as1*)g, (l_as3*)l, 16, 0, 0);
}

// ---------------------------------------------------------------------------
// Merged converts (one launch): ids [0,8192) = fp32->bf16 of query/context,
// ids [8192,9216) = weight transpose+convert fp32 [k][n] -> bf16 [n][k].
// Both read only original inputs -> dependency-legal merge.
// ---------------------------------------------------------------------------
__global__ __launch_bounds__(256) void cvt_all_kernel(
    const float* __restrict__ q, const float* __restrict__ c,
    ushort* __restrict__ qb, ushort* __restrict__ cb,
    const float* __restrict__ Wq, const float* __restrict__ Wk,
    const float* __restrict__ Wv, const float* __restrict__ Wo,
    ushort* __restrict__ wt)
{
    __shared__ float Ts[64 * 65];
    const int id = blockIdx.x;
    const int tid = threadIdx.x;

    if (id < 8192) {
        const float* src = (id >= 4096) ? c : q;
        ushort* dst = (id >= 4096) ? cb : qb;
        size_t i = ((size_t)(id & 4095) * 256 + tid) * 8;
        float4 v0 = *(const float4*)&src[i];
        float4 v1 = *(const float4*)&src[i + 4];
        uint4 o;
        o.x = pk_bf16(v0.x, v0.y); o.y = pk_bf16(v0.z, v0.w);
        o.z = pk_bf16(v1.x, v1.y); o.w = pk_bf16(v1.z, v1.w);
        *(uint4*)&dst[i] = o;
        return;
    }

    const int u = id - 8192;
    const int z = u >> 8;
    const float* W = (z == 0) ? Wq : (z == 1) ? Wk : (z == 2) ? Wv : Wo;
    ushort* WT = wt + (size_t)z * (1024 * 1024);
    const int n0 = (u & 15) * 64, k0 = ((u >> 4) & 15) * 64;

#pragma unroll
    for (int rr = 0; rr < 4; ++rr) {
        int uu = tid + rr * 256;
        int r = uu >> 4, cc = (uu & 15) * 4;
        float4 v = *(const float4*)&W[(size_t)(k0 + r) * 1024 + n0 + cc];
        Ts[r * 65 + cc + 0] = v.x; Ts[r * 65 + cc + 1] = v.y;
        Ts[r * 65 + cc + 2] = v.z; Ts[r * 65 + cc + 3] = v.w;
    }
    __syncthreads();
#pragma unroll
    for (int rr = 0; rr < 4; ++rr) {
        int uu = tid + rr * 256;
        int rn = uu >> 4, ck = (uu & 15) * 4;
        short4_t o;
        o[0] = f2b(Ts[(ck + 0) * 65 + rn]);
        o[1] = f2b(Ts[(ck + 1) * 65 + rn]);
        o[2] = f2b(Ts[(ck + 2) * 65 + rn]);
        o[3] = f2b(Ts[(ck + 3) * 65 + rn]);
        *(short4_t*)&WT[(size_t)(n0 + rn) * 1024 + k0 + ck] = o;
    }
}

// ---------------------------------------------------------------------------
// Merged Q/K/V projection (one launch, 1536 blocks):
//   ids [0,1024): K+V projection from Cb (mode 0=K, 1=V)
//   ids [1024,1536): Q projection from Qb (mode 2, scaled epilogue)
// All read only cvt outputs; identical K-loop body, 3-way epilogue.
// ---------------------------------------------------------------------------
__global__ __launch_bounds__(256) void proj_kernel(
    const ushort* __restrict__ Qb, const ushort* __restrict__ Cb,
    const ushort* __restrict__ WTbase,
    const float* __restrict__ biasq, const float* __restrict__ biask,
    const float* __restrict__ biasv,
    ushort* __restrict__ Qw, ushort* __restrict__ Kw, ushort* __restrict__ Vtw,
    float scale)
{
    __shared__ ushort As[128 * 64];
    __shared__ ushort Bs[128 * 64];
    const int tid = threadIdx.x;
    const int w = tid >> 6, lane = tid & 63;
    const int ln = tid & 15, quad = (tid >> 4) & 3;
    const int wm = w >> 1, wn = w & 1;

    const int id = blockIdx.x;
    int m0, n0, mode;
    const ushort* Ag;
    const ushort* BT;
    if (id < 1024) {
        mode = (id & 15) >> 3;                      // 0 = K, 1 = V
        n0 = (id & 7) * 128;
        m0 = (id >> 4) * 128;
        Ag = Cb;
        BT = WTbase + (size_t)(1 + mode) * 1048576; // Wk^T / Wv^T
    } else {
        int u = id - 1024;
        mode = 2;                                   // Q
        n0 = (u & 7) * 128;
        m0 = (u >> 3) * 128;
        Ag = Qb;
        BT = WTbase;                                // Wq^T
    }

    int offA[4], offB[4], lseg[4];
#pragma unroll
    for (int rr = 0; rr < 4; ++rr) {
        int idx = (rr * 4 + w) * 64 + lane;
        int r = idx >> 3, cst = idx & 7, csrc = cst ^ (r & 7);
        offA[rr] = (m0 + r) * 1024 + csrc * 8;
        offB[rr] = (n0 + r) * 1024 + csrc * 8;
        lseg[rr] = (rr * 4 + w) * 512;
    }

    f32x4 acc[4][4] = {};

    for (int kk = 0; kk < 1024; kk += 64) {
        __syncthreads();
#pragma unroll
        for (int rr = 0; rr < 4; ++rr)
            gll16(&Ag[(size_t)(offA[rr] + kk)], &As[lseg[rr]]);
#pragma unroll
        for (int rr = 0; rr < 4; ++rr)
            gll16(&BT[(size_t)(offB[rr] + kk)], &Bs[lseg[rr]]);
        __syncthreads();

#pragma unroll
        for (int ks = 0; ks < 2; ++ks) {
            short8 af[4], bfr[4];
#pragma unroll
            for (int i = 0; i < 4; ++i)
                af[i] = *(const short8*)&As[(wm * 64 + i * 16 + ln) * 64 +
                                            ((ks * 4 + quad) ^ (ln & 7)) * 8];
#pragma unroll
            for (int j = 0; j < 4; ++j)
                bfr[j] = *(const short8*)&Bs[(wn * 64 + j * 16 + ln) * 64 +
                                             ((ks * 4 + quad) ^ (ln & 7)) * 8];
#pragma unroll
            for (int i = 0; i < 4; ++i)
#pragma unroll
                for (int j = 0; j < 4; ++j)
                    acc[i][j] = MFMA16(af[i], bfr[j], acc[i][j]);
        }
    }

    if (mode == 1) {
        // V: transposed store [b,h,d,t]
#pragma unroll
        for (int j = 0; j < 4; ++j) {
            int n = n0 + wn * 64 + j * 16 + ln;
            int h = n >> 6, d = n & 63;
            float bvv = biasv[n];
#pragma unroll
            for (int i = 0; i < 4; ++i) {
                int mb = m0 + wm * 64 + i * 16 + quad * 4;
                int b = mb >> 11, t = mb & 2047;
                short4_t o;
                o[0] = f2b(acc[i][j][0] + bvv); o[1] = f2b(acc[i][j][1] + bvv);
                o[2] = f2b(acc[i][j][2] + bvv); o[3] = f2b(acc[i][j][3] + bvv);
                *(short4_t*)&Vtw[(((size_t)((b * 16 + h) * 64 + d)) << 11) + t] = o;
            }
        }
    } else {
        ushort* Out = (mode == 2) ? Qw : Kw;
        const float* bias = (mode == 2) ? biasq : biask;
        float sc = (mode == 2) ? scale : 1.0f;
#pragma unroll
        for (int j = 0; j < 4; ++j) {
            int n = n0 + wn * 64 + j * 16 + ln;
            int h = n >> 6, d = n & 63;
            float bvv = bias[n];
#pragma unroll
            for (int i = 0; i < 4; ++i) {
                int mb = m0 + wm * 64 + i * 16 + quad * 4;
#pragma unroll
                for (int r = 0; r < 4; ++r) {
                    int m = mb + r, b = m >> 11, t = m & 2047;
                    Out[(((size_t)(b * 16 + h) * 2048 + t) << 6) + d] =
                        (ushort)f2b((acc[i][j][r] + bvv) * sc);
                }
            }
        }
    }
}

// ---------------------------------------------------------------------------
// Output projection GEMM (unchanged): out fp32 row-major [m][n].
// ---------------------------------------------------------------------------
__global__ __launch_bounds__(256) void gemm_o_kernel(
    const ushort* __restrict__ Ag, const ushort* __restrict__ BT,
    const float* __restrict__ bias, float* __restrict__ Out)
{
    __shared__ ushort As[128 * 64];
    __shared__ ushort Bs[128 * 64];
    const int tid = threadIdx.x;
    const int w = tid >> 6, lane = tid & 63;
    const int ln = tid & 15, quad = (tid >> 4) & 3;
    const int wm = w >> 1, wn = w & 1;
    const int m0 = blockIdx.y * 128, n0 = blockIdx.x * 128;

    int offA[4], offB[4], lseg[4];
#pragma unroll
    for (int rr = 0; rr < 4; ++rr) {
        int idx = (rr * 4 + w) * 64 + lane;
        int r = idx >> 3, cst = idx & 7, csrc = cst ^ (r & 7);
        offA[rr] = (m0 + r) * 1024 + csrc * 8;
        offB[rr] = (n0 + r) * 1024 + csrc * 8;
        lseg[rr] = (rr * 4 + w) * 512;
    }

    f32x4 acc[4][4] = {};

    for (int kk = 0; kk < 1024; kk += 64) {
        __syncthreads();
#pragma unroll
        for (int rr = 0; rr < 4; ++rr)
            gll16(&Ag[(size_t)(offA[rr] + kk)], &As[lseg[rr]]);
#pragma unroll
        for (int rr = 0; rr < 4; ++rr)
            gll16(&BT[(size_t)(offB[rr] + kk)], &Bs[lseg[rr]]);
        __syncthreads();

#pragma unroll
        for (int ks = 0; ks < 2; ++ks) {
            short8 af[4], bfr[4];
#pragma unroll
            for (int i = 0; i < 4; ++i)
                af[i] = *(const short8*)&As[(wm * 64 + i * 16 + ln) * 64 +
                                            ((ks * 4 + quad) ^ (ln & 7)) * 8];
#pragma unroll
            for (int j = 0; j < 4; ++j)
                bfr[j] = *(const short8*)&Bs[(wn * 64 + j * 16 + ln) * 64 +
                                             ((ks * 4 + quad) ^ (ln & 7)) * 8];
#pragma unroll
            for (int i = 0; i < 4; ++i)
#pragma unroll
                for (int j = 0; j < 4; ++j)
                    acc[i][j] = MFMA16(af[i], bfr[j], acc[i][j]);
        }
    }

#pragma unroll
    for (int j = 0; j < 4; ++j) {
        int n = n0 + wn * 64 + j * 16 + ln;
        float bv = bias[n];
#pragma unroll
        for (int i = 0; i < 4; ++i) {
            int mb = m0 + wm * 64 + i * 16 + quad * 4;
#pragma unroll
            for (int r = 0; r < 4; ++r)
                Out[(size_t)(mb + r) * 1024 + n] = acc[i][j][r] + bv;
        }
    }
}

// ---------------------------------------------------------------------------
// Flash attention v8 = R3 structure (best measured: 95.6us, 805 TF) plus:
//  - batched ds_reads ahead of each MFMA cluster (ILP for the serial chain)
//  - s_setprio(1) around the QK and PV MFMA clusters (T5; m191: +4-7% attn)
// R2-R4 established: not memory-bound (FETCH 24MB, 5% HBM), not occupancy-
// bound (18-67% -> flat), not LDS-bytes-bound (4x traffic sweep -> flat).
// Dependency-bound in ds_read->QK->exp2->pack->PV chain at ~50% max pipe.
// 256 thr / 4 waves, 32 q-rows/wave, KVBLK=64 double-buffered, one barrier
// per tile, XCD-swizzled grid (all 16 q-tiles of a bh pin to one XCD).
// ---------------------------------------------------------------------------
__global__ __launch_bounds__(256, 4) void attn_kernel(
    const ushort* __restrict__ Qw, const ushort* __restrict__ Kw,
    const ushort* __restrict__ Vtw, ushort* __restrict__ attn)
{
    __shared__ ushort Ks[2][4096];      // 64 kv x 64 d, XOR chunk swizzle
    __shared__ ushort Vts[2][4096];     // 64 d  x 64 kv, XOR chunk swizzle

    const int tid = threadIdx.x;
    const int w = tid >> 6, lane = tid & 63;
    const int ln = tid & 15, quad = (tid >> 4) & 3;
    // XCD swizzle (bijective over 1024 = 8*128): xcd = id&7 = bh&7.
    const int id = blockIdx.x;
    const int qt = (id >> 3) & 15;
    const int bh = (id & 7) | ((id >> 7) << 3);
    const int b = bh >> 4, h = bh & 15;

    const ushort* Qg = Qw + (size_t)bh * 131072 + (size_t)qt * 8192;
    const ushort* Kg = Kw + (size_t)bh * 131072;
    const ushort* Vg = Vtw + (size_t)bh * 131072;

    // Q fragments (B-operand of K=32 QK): lane holds Q[q=w*32+qs*16+ln][d]
    short8 bq[2][2];
#pragma unroll
    for (int qs = 0; qs < 2; ++qs)
#pragma unroll
        for (int ks = 0; ks < 2; ++ks)
            bq[qs][ks] = *(const short8*)&Qg[(w * 32 + qs * 16 + ln) * 64 + ks * 32 + quad * 8];

    int offK[2], offV[2], lseg[2];
#pragma unroll
    for (int rr = 0; rr < 2; ++rr) {
        int idx = (rr * 4 + w) * 64 + lane;
        int r = idx >> 3, cst = idx & 7, csrc = cst ^ (r & 7);
        offK[rr] = r * 64 + csrc * 8;
        offV[rr] = r * 2048 + csrc * 8;
        lseg[rr] = (rr * 4 + w) * 512;
    }

    const short8 ones8 = {(short)0x3F80, (short)0x3F80, (short)0x3F80, (short)0x3F80,
                          (short)0x3F80, (short)0x3F80, (short)0x3F80, (short)0x3F80};

    f32x4 Of[2][4] = {};     // O^T: col = q = ln (qs slab), rows = d-local quad*4+r
    f32x4 lac[2] = {};       // col-sums of P: col = q = ln, rows all equal

    // prologue: stage tile 0 into buffer 0 (drained by the barrier below)
#pragma unroll
    for (int rr = 0; rr < 2; ++rr) gll16(&Kg[offK[rr]], &Ks[0][lseg[rr]]);
#pragma unroll
    for (int rr = 0; rr < 2; ++rr) gll16(&Vg[offV[rr]], &Vts[0][lseg[rr]]);
    __syncthreads();

    auto body = [&](int kt, const ushort* Kc, const ushort* Vc,
                    ushort* Kn, ushort* Vn) {
        // issue next tile's async global->LDS loads FIRST; the end-of-body
        // barrier's vmcnt(0) drain then overlaps this tile's compute.
        if (kt < 31) {
#pragma unroll
            for (int rr = 0; rr < 2; ++rr)
                gll16(&Kg[(kt + 1) * 4096 + offK[rr]], &Kn[lseg[rr]]);
#pragma unroll
            for (int rr = 0; rr < 2; ++rr)
                gll16(&Vg[(kt + 1) * 64 + offV[rr]], &Vn[lseg[rr]]);
        }

#pragma unroll
        for (int c = 0; c < 2; ++c) {
            // batch K fragment reads, then a pure-MFMA QK cluster
            short8 a0[2], a1[2];
#pragma unroll
            for (int kb = 0; kb < 2; ++kb) {
                int kv = 2 * c + kb;
                a0[kb] = *(const short8*)&Kc[(kv * 16 + ln) * 64 + (quad ^ (ln & 7)) * 8];
                a1[kb] = *(const short8*)&Kc[(kv * 16 + ln) * 64 + ((4 + quad) ^ (ln & 7)) * 8];
            }
            f32x4 s[2][2];
            __builtin_amdgcn_s_setprio(1);
#pragma unroll
            for (int kb = 0; kb < 2; ++kb)
#pragma unroll
                for (int qs = 0; qs < 2; ++qs) {
                    f32x4 t = {};
                    t = MFMA16(a0[kb], bq[qs][0], t);
                    t = MFMA16(a1[kb], bq[qs][1], t);
                    s[kb][qs] = t;
                }
            __builtin_amdgcn_s_setprio(0);

            // exp2 + pack into CONCATENATED K=32 B-operand (pi-permuted k)
            short8 pf8[2];
#pragma unroll
            for (int qs = 0; qs < 2; ++qs) {
                pk8_u pu;
                pu.u4[0] = pk_bf16(__builtin_amdgcn_exp2f(s[0][qs][0]),
                                   __builtin_amdgcn_exp2f(s[0][qs][1]));
                pu.u4[1] = pk_bf16(__builtin_amdgcn_exp2f(s[0][qs][2]),
                                   __builtin_amdgcn_exp2f(s[0][qs][3]));
                pu.u4[2] = pk_bf16(__builtin_amdgcn_exp2f(s[1][qs][0]),
                                   __builtin_amdgcn_exp2f(s[1][qs][1]));
                pu.u4[3] = pk_bf16(__builtin_amdgcn_exp2f(s[1][qs][2]),
                                   __builtin_amdgcn_exp2f(s[1][qs][3]));
                pf8[qs] = pu.s8;
                lac[qs] = MFMA16(ones8, pu.s8, lac[qs]);   // denominator, K=32
            }

            // batch V fragment reads, then a pure-MFMA PV cluster
            cat8_u av[4];
#pragma unroll
            for (int ds = 0; ds < 4; ++ds) {
                const ushort* vrow = &Vc[(ds * 16 + ln) * 64];
                av[ds].s4[0] = *(const short4_t*)&vrow[(((4 * c + (quad >> 1)) ^ (ln & 7)) * 8) + (quad & 1) * 4];
                av[ds].s4[1] = *(const short4_t*)&vrow[(((4 * c + 2 + (quad >> 1)) ^ (ln & 7)) * 8) + (quad & 1) * 4];
            }
            __builtin_amdgcn_s_setprio(1);
#pragma unroll
            for (int ds = 0; ds < 4; ++ds)
#pragma unroll
                for (int qs = 0; qs < 2; ++qs)
                    Of[qs][ds] = MFMA16(av[ds].s8, pf8[qs], Of[qs][ds]);
            __builtin_amdgcn_s_setprio(0);
        }

        // single barrier per tile: drains next-tile vmcnt (overlapped with the
        // compute above) AND guarantees all waves finished reading this buffer.
        __syncthreads();
    };

    for (int kt = 0; kt < 32; kt += 2) {
        body(kt,     Ks[0], Vts[0], Ks[1], Vts[1]);
        body(kt + 1, Ks[1], Vts[1], Ks[0], Vts[0]);
    }

    // finalize: lane ln owns q = w*32 + qs*16 + ln for both l and O columns
#pragma unroll
    for (int qs = 0; qs < 2; ++qs) {
        float inv = __builtin_amdgcn_rcpf(lac[qs][0]);
        int t = qt * 128 + w * 32 + qs * 16 + ln;
        size_t base = ((size_t)(b * 2048 + t) << 10) + h * 64;
#pragma unroll
        for (int ds = 0; ds < 4; ++ds) {
            uint2 o;
            o.x = pk_bf16(Of[qs][ds][0] * inv, Of[qs][ds][1] * inv);
            o.y = pk_bf16(Of[qs][ds][2] * inv, Of[qs][ds][3] * inv);
            *(uint2*)&attn[base + ds * 16 + quad * 4] = o;
        }
    }
}

// ---------------------------------------------------------------------------
extern "C" void kernel_launch(void* const* d_in, const int* in_sizes, int n_in,
                              void* d_out, int out_size, void* d_ws, size_t ws_size,
                              hipStream_t stream)
{
    const float* query   = (const float*)d_in[0];
    const float* context = (const float*)d_in[1];
    const float* Wq = (const float*)d_in[2];
    const float* bq = (const float*)d_in[3];
    const float* Wk = (const float*)d_in[4];
    const float* bk = (const float*)d_in[5];
    const float* Wv = (const float*)d_in[6];
    const float* bv = (const float*)d_in[7];
    const float* Wo = (const float*)d_in[8];
    const float* bo = (const float*)d_in[9];

    char* ws = (char*)d_ws;
    ushort* WT  = (ushort*)ws;                        // 4 x 2 MB bf16 [n][k]
    ushort* Qb  = (ushort*)(ws + 8388608);            // query bf16; later Aw
    ushort* Qw  = (ushort*)(ws + 25165824);           // [b,h,t,d] (pre-scaled)
    ushort* Kw  = (ushort*)(ws + 41943040);           // [b,h,t,d]
    ushort* Vtw = (ushort*)(ws + 58720256);           // [b,h,d,t]
    ushort* Aw  = Qb;                                 // attn out reuses Qb
    ushort* Cb  = (ushort*)d_out;                     // context bf16 in d_out

    const float SCALE = 0.18033688011112042f;         // log2(e)/sqrt(64)

    cvt_all_kernel<<<dim3(9216), 256, 0, stream>>>(query, context, Qb, Cb,
                                                   Wq, Wk, Wv, Wo, WT);
    proj_kernel<<<dim3(1536), 256, 0, stream>>>(Qb, Cb, WT, bq, bk, bv,
                                                Qw, Kw, Vtw, SCALE);
    attn_kernel<<<dim3(1024), 256, 0, stream>>>(Qw, Kw, Vtw, Aw);
    gemm_o_kernel<<<dim3(8, 64), 256, 0, stream>>>(Aw, WT + 3 * 1048576, bo,
                                                   (float*)d_out);
}

// Round 6
// 305.243 us; speedup vs baseline: 1.0799x; 1.0241x over previous
//
#include <hip/hip_runtime.h>
#include <hip/hip_bf16.h>
#include <cstdint>

typedef __attribute__((ext_vector_type(8))) short short8;
typedef __attribute__((ext_vector_type(4))) short short4_t;
typedef __attribute__((ext_vector_type(4))) float f32x4;

#define MFMA16(a, b, c) __builtin_amdgcn_mfma_f32_16x16x32_bf16(a, b, c, 0, 0, 0)

__device__ __forceinline__ short f2b(float f) {
    union { float fp; unsigned u; } un; un.fp = f;
    unsigned r = un.u + 0x7fffu + ((un.u >> 16) & 1u);
    return (short)(r >> 16);
}

// gfx950 has NO __builtin_amdgcn_cvt_pk_bf16_f32 (learn_hip m240) — the
// previous #if __has_builtin silently fell back to ~10 integer VALU ops per
// pack. The HW instruction exists; use it directly. RNE rounding == f2b.
// dst.lo = cvt(a), dst.hi = cvt(b).
__device__ __forceinline__ unsigned pk_bf16(float a, float b) {
    unsigned r;
    asm("v_cvt_pk_bf16_f32 %0, %1, %2" : "=v"(r) : "v"(a), "v"(b));
    return r;
}

union pk8_u { unsigned u4[4]; short8 s8; };
union pk4_u { unsigned u2[2]; short4_t s4; };
union cat8_u { short4_t s4[2]; short8 s8; };

typedef const __attribute__((address_space(1))) unsigned g_as1;
typedef __attribute__((address_space(3))) unsigned l_as3;
__device__ __forceinline__ void gll16(const ushort* g, ushort* l) {
    __builtin_amdgcn_global_load_lds((g_as1*)g, (l_as3*)l, 16, 0, 0);
}

// ---------------------------------------------------------------------------
// Merged converts (one launch): ids [0,8192) = fp32->bf16 of query/context,
// ids [8192,9216) = weight transpose+convert fp32 [k][n] -> bf16 [n][k].
// Both read only original inputs -> dependency-legal merge.
// ---------------------------------------------------------------------------
__global__ __launch_bounds__(256) void cvt_all_kernel(
    const float* __restrict__ q, const float* __restrict__ c,
    ushort* __restrict__ qb, ushort* __restrict__ cb,
    const float* __restrict__ Wq, const float* __restrict__ Wk,
    const float* __restrict__ Wv, const float* __restrict__ Wo,
    ushort* __restrict__ wt)
{
    __shared__ float Ts[64 * 65];
    const int id = blockIdx.x;
    const int tid = threadIdx.x;

    if (id < 8192) {
        const float* src = (id >= 4096) ? c : q;
        ushort* dst = (id >= 4096) ? cb : qb;
        size_t i = ((size_t)(id & 4095) * 256 + tid) * 8;
        float4 v0 = *(const float4*)&src[i];
        float4 v1 = *(const float4*)&src[i + 4];
        uint4 o;
        o.x = pk_bf16(v0.x, v0.y); o.y = pk_bf16(v0.z, v0.w);
        o.z = pk_bf16(v1.x, v1.y); o.w = pk_bf16(v1.z, v1.w);
        *(uint4*)&dst[i] = o;
        return;
    }

    const int u = id - 8192;
    const int z = u >> 8;
    const float* W = (z == 0) ? Wq : (z == 1) ? Wk : (z == 2) ? Wv : Wo;
    ushort* WT = wt + (size_t)z * (1024 * 1024);
    const int n0 = (u & 15) * 64, k0 = ((u >> 4) & 15) * 64;

#pragma unroll
    for (int rr = 0; rr < 4; ++rr) {
        int uu = tid + rr * 256;
        int r = uu >> 4, cc = (uu & 15) * 4;
        float4 v = *(const float4*)&W[(size_t)(k0 + r) * 1024 + n0 + cc];
        Ts[r * 65 + cc + 0] = v.x; Ts[r * 65 + cc + 1] = v.y;
        Ts[r * 65 + cc + 2] = v.z; Ts[r * 65 + cc + 3] = v.w;
    }
    __syncthreads();
#pragma unroll
    for (int rr = 0; rr < 4; ++rr) {
        int uu = tid + rr * 256;
        int rn = uu >> 4, ck = (uu & 15) * 4;
        pk4_u o;
        o.u2[0] = pk_bf16(Ts[(ck + 0) * 65 + rn], Ts[(ck + 1) * 65 + rn]);
        o.u2[1] = pk_bf16(Ts[(ck + 2) * 65 + rn], Ts[(ck + 3) * 65 + rn]);
        *(short4_t*)&WT[(size_t)(n0 + rn) * 1024 + k0 + ck] = o.s4;
    }
}

// ---------------------------------------------------------------------------
// Merged Q/K/V projection (one launch, 1536 blocks):
//   ids [0,1024): K+V projection from Cb (mode 0=K, 1=V)
//   ids [1024,1536): Q projection from Qb (mode 2, scaled epilogue)
// All read only cvt outputs; identical K-loop body, 3-way epilogue.
// ---------------------------------------------------------------------------
__global__ __launch_bounds__(256) void proj_kernel(
    const ushort* __restrict__ Qb, const ushort* __restrict__ Cb,
    const ushort* __restrict__ WTbase,
    const float* __restrict__ biasq, const float* __restrict__ biask,
    const float* __restrict__ biasv,
    ushort* __restrict__ Qw, ushort* __restrict__ Kw, ushort* __restrict__ Vtw,
    float scale)
{
    __shared__ ushort As[128 * 64];
    __shared__ ushort Bs[128 * 64];
    const int tid = threadIdx.x;
    const int w = tid >> 6, lane = tid & 63;
    const int ln = tid & 15, quad = (tid >> 4) & 3;
    const int wm = w >> 1, wn = w & 1;

    const int id = blockIdx.x;
    int m0, n0, mode;
    const ushort* Ag;
    const ushort* BT;
    if (id < 1024) {
        mode = (id & 15) >> 3;                      // 0 = K, 1 = V
        n0 = (id & 7) * 128;
        m0 = (id >> 4) * 128;
        Ag = Cb;
        BT = WTbase + (size_t)(1 + mode) * 1048576; // Wk^T / Wv^T
    } else {
        int u = id - 1024;
        mode = 2;                                   // Q
        n0 = (u & 7) * 128;
        m0 = (u >> 3) * 128;
        Ag = Qb;
        BT = WTbase;                                // Wq^T
    }

    int offA[4], offB[4], lseg[4];
#pragma unroll
    for (int rr = 0; rr < 4; ++rr) {
        int idx = (rr * 4 + w) * 64 + lane;
        int r = idx >> 3, cst = idx & 7, csrc = cst ^ (r & 7);
        offA[rr] = (m0 + r) * 1024 + csrc * 8;
        offB[rr] = (n0 + r) * 1024 + csrc * 8;
        lseg[rr] = (rr * 4 + w) * 512;
    }

    f32x4 acc[4][4] = {};

    for (int kk = 0; kk < 1024; kk += 64) {
        __syncthreads();
#pragma unroll
        for (int rr = 0; rr < 4; ++rr)
            gll16(&Ag[(size_t)(offA[rr] + kk)], &As[lseg[rr]]);
#pragma unroll
        for (int rr = 0; rr < 4; ++rr)
            gll16(&BT[(size_t)(offB[rr] + kk)], &Bs[lseg[rr]]);
        __syncthreads();

#pragma unroll
        for (int ks = 0; ks < 2; ++ks) {
            short8 af[4], bfr[4];
#pragma unroll
            for (int i = 0; i < 4; ++i)
                af[i] = *(const short8*)&As[(wm * 64 + i * 16 + ln) * 64 +
                                            ((ks * 4 + quad) ^ (ln & 7)) * 8];
#pragma unroll
            for (int j = 0; j < 4; ++j)
                bfr[j] = *(const short8*)&Bs[(wn * 64 + j * 16 + ln) * 64 +
                                             ((ks * 4 + quad) ^ (ln & 7)) * 8];
#pragma unroll
            for (int i = 0; i < 4; ++i)
#pragma unroll
                for (int j = 0; j < 4; ++j)
                    acc[i][j] = MFMA16(af[i], bfr[j], acc[i][j]);
        }
    }

    if (mode == 1) {
        // V: transposed store [b,h,d,t]
#pragma unroll
        for (int j = 0; j < 4; ++j) {
            int n = n0 + wn * 64 + j * 16 + ln;
            int h = n >> 6, d = n & 63;
            float bvv = biasv[n];
#pragma unroll
            for (int i = 0; i < 4; ++i) {
                int mb = m0 + wm * 64 + i * 16 + quad * 4;
                int b = mb >> 11, t = mb & 2047;
                pk4_u o;
                o.u2[0] = pk_bf16(acc[i][j][0] + bvv, acc[i][j][1] + bvv);
                o.u2[1] = pk_bf16(acc[i][j][2] + bvv, acc[i][j][3] + bvv);
                *(short4_t*)&Vtw[(((size_t)((b * 16 + h) * 64 + d)) << 11) + t] = o.s4;
            }
        }
    } else {
        ushort* Out = (mode == 2) ? Qw : Kw;
        const float* bias = (mode == 2) ? biasq : biask;
        float sc = (mode == 2) ? scale : 1.0f;
#pragma unroll
        for (int j = 0; j < 4; ++j) {
            int n = n0 + wn * 64 + j * 16 + ln;
            int h = n >> 6, d = n & 63;
            float bvv = bias[n];
#pragma unroll
            for (int i = 0; i < 4; ++i) {
                int mb = m0 + wm * 64 + i * 16 + quad * 4;
#pragma unroll
                for (int r = 0; r < 4; ++r) {
                    int m = mb + r, b = m >> 11, t = m & 2047;
                    Out[(((size_t)(b * 16 + h) * 2048 + t) << 6) + d] =
                        (ushort)f2b((acc[i][j][r] + bvv) * sc);
                }
            }
        }
    }
}

// ---------------------------------------------------------------------------
// Output projection GEMM (unchanged): out fp32 row-major [m][n].
// ---------------------------------------------------------------------------
__global__ __launch_bounds__(256) void gemm_o_kernel(
    const ushort* __restrict__ Ag, const ushort* __restrict__ BT,
    const float* __restrict__ bias, float* __restrict__ Out)
{
    __shared__ ushort As[128 * 64];
    __shared__ ushort Bs[128 * 64];
    const int tid = threadIdx.x;
    const int w = tid >> 6, lane = tid & 63;
    const int ln = tid & 15, quad = (tid >> 4) & 3;
    const int wm = w >> 1, wn = w & 1;
    const int m0 = blockIdx.y * 128, n0 = blockIdx.x * 128;

    int offA[4], offB[4], lseg[4];
#pragma unroll
    for (int rr = 0; rr < 4; ++rr) {
        int idx = (rr * 4 + w) * 64 + lane;
        int r = idx >> 3, cst = idx & 7, csrc = cst ^ (r & 7);
        offA[rr] = (m0 + r) * 1024 + csrc * 8;
        offB[rr] = (n0 + r) * 1024 + csrc * 8;
        lseg[rr] = (rr * 4 + w) * 512;
    }

    f32x4 acc[4][4] = {};

    for (int kk = 0; kk < 1024; kk += 64) {
        __syncthreads();
#pragma unroll
        for (int rr = 0; rr < 4; ++rr)
            gll16(&Ag[(size_t)(offA[rr] + kk)], &As[lseg[rr]]);
#pragma unroll
        for (int rr = 0; rr < 4; ++rr)
            gll16(&BT[(size_t)(offB[rr] + kk)], &Bs[lseg[rr]]);
        __syncthreads();

#pragma unroll
        for (int ks = 0; ks < 2; ++ks) {
            short8 af[4], bfr[4];
#pragma unroll
            for (int i = 0; i < 4; ++i)
                af[i] = *(const short8*)&As[(wm * 64 + i * 16 + ln) * 64 +
                                            ((ks * 4 + quad) ^ (ln & 7)) * 8];
#pragma unroll
            for (int j = 0; j < 4; ++j)
                bfr[j] = *(const short8*)&Bs[(wn * 64 + j * 16 + ln) * 64 +
                                             ((ks * 4 + quad) ^ (ln & 7)) * 8];
#pragma unroll
            for (int i = 0; i < 4; ++i)
#pragma unroll
                for (int j = 0; j < 4; ++j)
                    acc[i][j] = MFMA16(af[i], bfr[j], acc[i][j]);
        }
    }

#pragma unroll
    for (int j = 0; j < 4; ++j) {
        int n = n0 + wn * 64 + j * 16 + ln;
        float bv = bias[n];
#pragma unroll
        for (int i = 0; i < 4; ++i) {
            int mb = m0 + wm * 64 + i * 16 + quad * 4;
#pragma unroll
            for (int r = 0; r < 4; ++r)
                Out[(size_t)(mb + r) * 1024 + n] = acc[i][j][r] + bv;
        }
    }
}

// ---------------------------------------------------------------------------
// Flash attention v9 = R5 structure with hardware cvt_pk packing.
// R2-R5 established: not memory-, occupancy-, LDS-bytes-, or schedule-bound;
// every pipe <=58%. The VALU budget was dominated by the silent pk_bf16
// fallback (~10 int ops/pack, in the serial QK->exp2->pack->PV chain).
// v_cvt_pk_bf16_f32 inline asm cuts that to 1 instr/pack.
// 256 thr / 4 waves, 32 q-rows/wave, KVBLK=64 double-buffered, one barrier
// per tile, XCD-swizzled grid, setprio around MFMA clusters.
// ---------------------------------------------------------------------------
__global__ __launch_bounds__(256, 4) void attn_kernel(
    const ushort* __restrict__ Qw, const ushort* __restrict__ Kw,
    const ushort* __restrict__ Vtw, ushort* __restrict__ attn)
{
    __shared__ ushort Ks[2][4096];      // 64 kv x 64 d, XOR chunk swizzle
    __shared__ ushort Vts[2][4096];     // 64 d  x 64 kv, XOR chunk swizzle

    const int tid = threadIdx.x;
    const int w = tid >> 6, lane = tid & 63;
    const int ln = tid & 15, quad = (tid >> 4) & 3;
    // XCD swizzle (bijective over 1024 = 8*128): xcd = id&7 = bh&7.
    const int id = blockIdx.x;
    const int qt = (id >> 3) & 15;
    const int bh = (id & 7) | ((id >> 7) << 3);
    const int b = bh >> 4, h = bh & 15;

    const ushort* Qg = Qw + (size_t)bh * 131072 + (size_t)qt * 8192;
    const ushort* Kg = Kw + (size_t)bh * 131072;
    const ushort* Vg = Vtw + (size_t)bh * 131072;

    // Q fragments (B-operand of K=32 QK): lane holds Q[q=w*32+qs*16+ln][d]
    short8 bq[2][2];
#pragma unroll
    for (int qs = 0; qs < 2; ++qs)
#pragma unroll
        for (int ks = 0; ks < 2; ++ks)
            bq[qs][ks] = *(const short8*)&Qg[(w * 32 + qs * 16 + ln) * 64 + ks * 32 + quad * 8];

    int offK[2], offV[2], lseg[2];
#pragma unroll
    for (int rr = 0; rr < 2; ++rr) {
        int idx = (rr * 4 + w) * 64 + lane;
        int r = idx >> 3, cst = idx & 7, csrc = cst ^ (r & 7);
        offK[rr] = r * 64 + csrc * 8;
        offV[rr] = r * 2048 + csrc * 8;
        lseg[rr] = (rr * 4 + w) * 512;
    }

    const short8 ones8 = {(short)0x3F80, (short)0x3F80, (short)0x3F80, (short)0x3F80,
                          (short)0x3F80, (short)0x3F80, (short)0x3F80, (short)0x3F80};

    f32x4 Of[2][4] = {};     // O^T: col = q = ln (qs slab), rows = d-local quad*4+r
    f32x4 lac[2] = {};       // col-sums of P: col = q = ln, rows all equal

    // prologue: stage tile 0 into buffer 0 (drained by the barrier below)
#pragma unroll
    for (int rr = 0; rr < 2; ++rr) gll16(&Kg[offK[rr]], &Ks[0][lseg[rr]]);
#pragma unroll
    for (int rr = 0; rr < 2; ++rr) gll16(&Vg[offV[rr]], &Vts[0][lseg[rr]]);
    __syncthreads();

    auto body = [&](int kt, const ushort* Kc, const ushort* Vc,
                    ushort* Kn, ushort* Vn) {
        // issue next tile's async global->LDS loads FIRST; the end-of-body
        // barrier's vmcnt(0) drain then overlaps this tile's compute.
        if (kt < 31) {
#pragma unroll
            for (int rr = 0; rr < 2; ++rr)
                gll16(&Kg[(kt + 1) * 4096 + offK[rr]], &Kn[lseg[rr]]);
#pragma unroll
            for (int rr = 0; rr < 2; ++rr)
                gll16(&Vg[(kt + 1) * 64 + offV[rr]], &Vn[lseg[rr]]);
        }

#pragma unroll
        for (int c = 0; c < 2; ++c) {
            // batch K fragment reads, then a pure-MFMA QK cluster
            short8 a0[2], a1[2];
#pragma unroll
            for (int kb = 0; kb < 2; ++kb) {
                int kv = 2 * c + kb;
                a0[kb] = *(const short8*)&Kc[(kv * 16 + ln) * 64 + (quad ^ (ln & 7)) * 8];
                a1[kb] = *(const short8*)&Kc[(kv * 16 + ln) * 64 + ((4 + quad) ^ (ln & 7)) * 8];
            }
            f32x4 s[2][2];
            __builtin_amdgcn_s_setprio(1);
#pragma unroll
            for (int kb = 0; kb < 2; ++kb)
#pragma unroll
                for (int qs = 0; qs < 2; ++qs) {
                    f32x4 t = {};
                    t = MFMA16(a0[kb], bq[qs][0], t);
                    t = MFMA16(a1[kb], bq[qs][1], t);
                    s[kb][qs] = t;
                }
            __builtin_amdgcn_s_setprio(0);

            // exp2 + hardware pack into CONCATENATED K=32 B-operand
            short8 pf8[2];
#pragma unroll
            for (int qs = 0; qs < 2; ++qs) {
                pk8_u pu;
                pu.u4[0] = pk_bf16(__builtin_amdgcn_exp2f(s[0][qs][0]),
                                   __builtin_amdgcn_exp2f(s[0][qs][1]));
                pu.u4[1] = pk_bf16(__builtin_amdgcn_exp2f(s[0][qs][2]),
                                   __builtin_amdgcn_exp2f(s[0][qs][3]));
                pu.u4[2] = pk_bf16(__builtin_amdgcn_exp2f(s[1][qs][0]),
                                   __builtin_amdgcn_exp2f(s[1][qs][1]));
                pu.u4[3] = pk_bf16(__builtin_amdgcn_exp2f(s[1][qs][2]),
                                   __builtin_amdgcn_exp2f(s[1][qs][3]));
                pf8[qs] = pu.s8;
                lac[qs] = MFMA16(ones8, pu.s8, lac[qs]);   // denominator, K=32
            }

            // batch V fragment reads, then a pure-MFMA PV cluster
            cat8_u av[4];
#pragma unroll
            for (int ds = 0; ds < 4; ++ds) {
                const ushort* vrow = &Vc[(ds * 16 + ln) * 64];
                av[ds].s4[0] = *(const short4_t*)&vrow[(((4 * c + (quad >> 1)) ^ (ln & 7)) * 8) + (quad & 1) * 4];
                av[ds].s4[1] = *(const short4_t*)&vrow[(((4 * c + 2 + (quad >> 1)) ^ (ln & 7)) * 8) + (quad & 1) * 4];
            }
            __builtin_amdgcn_s_setprio(1);
#pragma unroll
            for (int ds = 0; ds < 4; ++ds)
#pragma unroll
                for (int qs = 0; qs < 2; ++qs)
                    Of[qs][ds] = MFMA16(av[ds].s8, pf8[qs], Of[qs][ds]);
            __builtin_amdgcn_s_setprio(0);
        }

        // single barrier per tile: drains next-tile vmcnt (overlapped with the
        // compute above) AND guarantees all waves finished reading this buffer.
        __syncthreads();
    };

    for (int kt = 0; kt < 32; kt += 2) {
        body(kt,     Ks[0], Vts[0], Ks[1], Vts[1]);
        body(kt + 1, Ks[1], Vts[1], Ks[0], Vts[0]);
    }

    // finalize: lane ln owns q = w*32 + qs*16 + ln for both l and O columns
#pragma unroll
    for (int qs = 0; qs < 2; ++qs) {
        float inv = __builtin_amdgcn_rcpf(lac[qs][0]);
        int t = qt * 128 + w * 32 + qs * 16 + ln;
        size_t base = ((size_t)(b * 2048 + t) << 10) + h * 64;
#pragma unroll
        for (int ds = 0; ds < 4; ++ds) {
            uint2 o;
            o.x = pk_bf16(Of[qs][ds][0] * inv, Of[qs][ds][1] * inv);
            o.y = pk_bf16(Of[qs][ds][2] * inv, Of[qs][ds][3] * inv);
            *(uint2*)&attn[base + ds * 16 + quad * 4] = o;
        }
    }
}

// ---------------------------------------------------------------------------
extern "C" void kernel_launch(void* const* d_in, const int* in_sizes, int n_in,
                              void* d_out, int out_size, void* d_ws, size_t ws_size,
                              hipStream_t stream)
{
    const float* query   = (const float*)d_in[0];
    const float* context = (const float*)d_in[1];
    const float* Wq = (const float*)d_in[2];
    const float* bq = (const float*)d_in[3];
    const float* Wk = (const float*)d_in[4];
    const float* bk = (const float*)d_in[5];
    const float* Wv = (const float*)d_in[6];
    const float* bv = (const float*)d_in[7];
    const float* Wo = (const float*)d_in[8];
    const float* bo = (const float*)d_in[9];

    char* ws = (char*)d_ws;
    ushort* WT  = (ushort*)ws;                        // 4 x 2 MB bf16 [n][k]
    ushort* Qb  = (ushort*)(ws + 8388608);            // query bf16; later Aw
    ushort* Qw  = (ushort*)(ws + 25165824);           // [b,h,t,d] (pre-scaled)
    ushort* Kw  = (ushort*)(ws + 41943040);           // [b,h,t,d]
    ushort* Vtw = (ushort*)(ws + 58720256);           // [b,h,d,t]
    ushort* Aw  = Qb;                                 // attn out reuses Qb
    ushort* Cb  = (ushort*)d_out;                     // context bf16 in d_out

    const float SCALE = 0.18033688011112042f;         // log2(e)/sqrt(64)

    cvt_all_kernel<<<dim3(9216), 256, 0, stream>>>(query, context, Qb, Cb,
                                                   Wq, Wk, Wv, Wo, WT);
    proj_kernel<<<dim3(1536), 256, 0, stream>>>(Qb, Cb, WT, bq, bk, bv,
                                                Qw, Kw, Vtw, SCALE);
    attn_kernel<<<dim3(1024), 256, 0, stream>>>(Qw, Kw, Vtw, Aw);
    gemm_o_kernel<<<dim3(8, 64), 256, 0, stream>>>(Aw, WT + 3 * 1048576, bo,
                                                   (float*)d_out);
}

// Round 7
// 300.618 us; speedup vs baseline: 1.0965x; 1.0154x over previous
//
#include <hip/hip_runtime.h>
#include <hip/hip_bf16.h>
#include <cstdint>

typedef __attribute__((ext_vector_type(8))) short short8;
typedef __attribute__((ext_vector_type(4))) short short4_t;
typedef __attribute__((ext_vector_type(4))) float f32x4;

#define MFMA16(a, b, c) __builtin_amdgcn_mfma_f32_16x16x32_bf16(a, b, c, 0, 0, 0)

__device__ __forceinline__ short f2b(float f) {
    union { float fp; unsigned u; } un; un.fp = f;
    unsigned r = un.u + 0x7fffu + ((un.u >> 16) & 1u);
    return (short)(r >> 16);
}

// gfx950 has NO __builtin_amdgcn_cvt_pk_bf16_f32 (learn_hip m240); use the
// HW instruction directly. RNE rounding == f2b. dst.lo=cvt(a), dst.hi=cvt(b).
__device__ __forceinline__ unsigned pk_bf16(float a, float b) {
    unsigned r;
    asm("v_cvt_pk_bf16_f32 %0, %1, %2" : "=v"(r) : "v"(a), "v"(b));
    return r;
}

union pk8_u { unsigned u4[4]; short8 s8; };
union pk4_u { unsigned u2[2]; short4_t s4; };
union cat8_u { short4_t s4[2]; short8 s8; };

typedef const __attribute__((address_space(1))) unsigned g_as1;
typedef __attribute__((address_space(3))) unsigned l_as3;
__device__ __forceinline__ void gll16(const ushort* g, ushort* l) {
    __builtin_amdgcn_global_load_lds((g_as1*)g, (l_as3*)l, 16, 0, 0);
}

// ---------------------------------------------------------------------------
// Merged converts (one launch): ids [0,8192) = fp32->bf16 of query/context,
// ids [8192,9216) = weight transpose+convert fp32 [k][n] -> bf16 [n][k].
// Streaming, no inter-block reuse -> no XCD swizzle needed (T1 null there).
// ---------------------------------------------------------------------------
__global__ __launch_bounds__(256) void cvt_all_kernel(
    const float* __restrict__ q, const float* __restrict__ c,
    ushort* __restrict__ qb, ushort* __restrict__ cb,
    const float* __restrict__ Wq, const float* __restrict__ Wk,
    const float* __restrict__ Wv, const float* __restrict__ Wo,
    ushort* __restrict__ wt)
{
    __shared__ float Ts[64 * 65];
    const int id = blockIdx.x;
    const int tid = threadIdx.x;

    if (id < 8192) {
        const float* src = (id >= 4096) ? c : q;
        ushort* dst = (id >= 4096) ? cb : qb;
        size_t i = ((size_t)(id & 4095) * 256 + tid) * 8;
        float4 v0 = *(const float4*)&src[i];
        float4 v1 = *(const float4*)&src[i + 4];
        uint4 o;
        o.x = pk_bf16(v0.x, v0.y); o.y = pk_bf16(v0.z, v0.w);
        o.z = pk_bf16(v1.x, v1.y); o.w = pk_bf16(v1.z, v1.w);
        *(uint4*)&dst[i] = o;
        return;
    }

    const int u = id - 8192;
    const int z = u >> 8;
    const float* W = (z == 0) ? Wq : (z == 1) ? Wk : (z == 2) ? Wv : Wo;
    ushort* WT = wt + (size_t)z * (1024 * 1024);
    const int n0 = (u & 15) * 64, k0 = ((u >> 4) & 15) * 64;

#pragma unroll
    for (int rr = 0; rr < 4; ++rr) {
        int uu = tid + rr * 256;
        int r = uu >> 4, cc = (uu & 15) * 4;
        float4 v = *(const float4*)&W[(size_t)(k0 + r) * 1024 + n0 + cc];
        Ts[r * 65 + cc + 0] = v.x; Ts[r * 65 + cc + 1] = v.y;
        Ts[r * 65 + cc + 2] = v.z; Ts[r * 65 + cc + 3] = v.w;
    }
    __syncthreads();
#pragma unroll
    for (int rr = 0; rr < 4; ++rr) {
        int uu = tid + rr * 256;
        int rn = uu >> 4, ck = (uu & 15) * 4;
        pk4_u o;
        o.u2[0] = pk_bf16(Ts[(ck + 0) * 65 + rn], Ts[(ck + 1) * 65 + rn]);
        o.u2[1] = pk_bf16(Ts[(ck + 2) * 65 + rn], Ts[(ck + 3) * 65 + rn]);
        *(short4_t*)&WT[(size_t)(n0 + rn) * 1024 + k0 + ck] = o.s4;
    }
}

// ---------------------------------------------------------------------------
// Merged Q/K/V projection, XCD-chunked (R6 diagnosis: FETCH=136MB vs 22MB
// compulsory because id&7 = n-tile = XCD -> the 8 blocks sharing an A-tile
// sat on 8 different L2s). Remap: lid = (hw&7)*192 + hw>>3 gives each XCD a
// contiguous lid range; decode lid n-fastest, then m, mode slowest. Per-XCD
// steady working set = weight (2MB) + A-tile (256KB) < 4MB L2.
//   lid [0,512): K   lid [512,1024): V   lid [1024,1536): Q
// ---------------------------------------------------------------------------
__global__ __launch_bounds__(256) void proj_kernel(
    const ushort* __restrict__ Qb, const ushort* __restrict__ Cb,
    const ushort* __restrict__ WTbase,
    const float* __restrict__ biasq, const float* __restrict__ biask,
    const float* __restrict__ biasv,
    ushort* __restrict__ Qw, ushort* __restrict__ Kw, ushort* __restrict__ Vtw,
    float scale)
{
    __shared__ ushort As[128 * 64];
    __shared__ ushort Bs[128 * 64];
    const int tid = threadIdx.x;
    const int w = tid >> 6, lane = tid & 63;
    const int ln = tid & 15, quad = (tid >> 4) & 3;
    const int wm = w >> 1, wn = w & 1;

    const int hw = blockIdx.x;
    const int lid = (hw & 7) * 192 + (hw >> 3);   // XCD-contiguous (1536=8*192)
    const int mode = lid >> 9;                    // 0=K, 1=V, 2=Q
    const int rem = lid & 511;
    const int m0 = (rem >> 3) * 128;
    const int n0 = (rem & 7) * 128;
    const ushort* Ag = (mode == 2) ? Qb : Cb;
    const ushort* BT = (mode == 2) ? WTbase : WTbase + (size_t)(1 + mode) * 1048576;

    int offA[4], offB[4], lseg[4];
#pragma unroll
    for (int rr = 0; rr < 4; ++rr) {
        int idx = (rr * 4 + w) * 64 + lane;
        int r = idx >> 3, cst = idx & 7, csrc = cst ^ (r & 7);
        offA[rr] = (m0 + r) * 1024 + csrc * 8;
        offB[rr] = (n0 + r) * 1024 + csrc * 8;
        lseg[rr] = (rr * 4 + w) * 512;
    }

    f32x4 acc[4][4] = {};

    for (int kk = 0; kk < 1024; kk += 64) {
        __syncthreads();
#pragma unroll
        for (int rr = 0; rr < 4; ++rr)
            gll16(&Ag[(size_t)(offA[rr] + kk)], &As[lseg[rr]]);
#pragma unroll
        for (int rr = 0; rr < 4; ++rr)
            gll16(&BT[(size_t)(offB[rr] + kk)], &Bs[lseg[rr]]);
        __syncthreads();

#pragma unroll
        for (int ks = 0; ks < 2; ++ks) {
            short8 af[4], bfr[4];
#pragma unroll
            for (int i = 0; i < 4; ++i)
                af[i] = *(const short8*)&As[(wm * 64 + i * 16 + ln) * 64 +
                                            ((ks * 4 + quad) ^ (ln & 7)) * 8];
#pragma unroll
            for (int j = 0; j < 4; ++j)
                bfr[j] = *(const short8*)&Bs[(wn * 64 + j * 16 + ln) * 64 +
                                             ((ks * 4 + quad) ^ (ln & 7)) * 8];
#pragma unroll
            for (int i = 0; i < 4; ++i)
#pragma unroll
                for (int j = 0; j < 4; ++j)
                    acc[i][j] = MFMA16(af[i], bfr[j], acc[i][j]);
        }
    }

    if (mode == 1) {
        // V: transposed store [b,h,d,t]
#pragma unroll
        for (int j = 0; j < 4; ++j) {
            int n = n0 + wn * 64 + j * 16 + ln;
            int h = n >> 6, d = n & 63;
            float bvv = biasv[n];
#pragma unroll
            for (int i = 0; i < 4; ++i) {
                int mb = m0 + wm * 64 + i * 16 + quad * 4;
                int b = mb >> 11, t = mb & 2047;
                pk4_u o;
                o.u2[0] = pk_bf16(acc[i][j][0] + bvv, acc[i][j][1] + bvv);
                o.u2[1] = pk_bf16(acc[i][j][2] + bvv, acc[i][j][3] + bvv);
                *(short4_t*)&Vtw[(((size_t)((b * 16 + h) * 64 + d)) << 11) + t] = o.s4;
            }
        }
    } else {
        ushort* Out = (mode == 2) ? Qw : Kw;
        const float* bias = (mode == 2) ? biasq : biask;
        float sc = (mode == 2) ? scale : 1.0f;
#pragma unroll
        for (int j = 0; j < 4; ++j) {
            int n = n0 + wn * 64 + j * 16 + ln;
            int h = n >> 6, d = n & 63;
            float bvv = bias[n];
#pragma unroll
            for (int i = 0; i < 4; ++i) {
                int mb = m0 + wm * 64 + i * 16 + quad * 4;
#pragma unroll
                for (int r = 0; r < 4; ++r) {
                    int m = mb + r, b = m >> 11, t = m & 2047;
                    Out[(((size_t)(b * 16 + h) * 2048 + t) << 6) + d] =
                        (ushort)f2b((acc[i][j][r] + bvv) * sc);
                }
            }
        }
    }
}

// ---------------------------------------------------------------------------
// Output projection GEMM, XCD-chunked like proj: flat 512 grid,
// lid = (hw&7)*64 + hw>>3; n fastest, m slower. Per-XCD working set =
// Wo^T (2MB) + one A-tile (256KB) < L2.
// ---------------------------------------------------------------------------
__global__ __launch_bounds__(256) void gemm_o_kernel(
    const ushort* __restrict__ Ag, const ushort* __restrict__ BT,
    const float* __restrict__ bias, float* __restrict__ Out)
{
    __shared__ ushort As[128 * 64];
    __shared__ ushort Bs[128 * 64];
    const int tid = threadIdx.x;
    const int w = tid >> 6, lane = tid & 63;
    const int ln = tid & 15, quad = (tid >> 4) & 3;
    const int wm = w >> 1, wn = w & 1;
    const int hw = blockIdx.x;
    const int lid = (hw & 7) * 64 + (hw >> 3);    // XCD-contiguous (512=8*64)
    const int m0 = (lid >> 3) * 128, n0 = (lid & 7) * 128;

    int offA[4], offB[4], lseg[4];
#pragma unroll
    for (int rr = 0; rr < 4; ++rr) {
        int idx = (rr * 4 + w) * 64 + lane;
        int r = idx >> 3, cst = idx & 7, csrc = cst ^ (r & 7);
        offA[rr] = (m0 + r) * 1024 + csrc * 8;
        offB[rr] = (n0 + r) * 1024 + csrc * 8;
        lseg[rr] = (rr * 4 + w) * 512;
    }

    f32x4 acc[4][4] = {};

    for (int kk = 0; kk < 1024; kk += 64) {
        __syncthreads();
#pragma unroll
        for (int rr = 0; rr < 4; ++rr)
            gll16(&Ag[(size_t)(offA[rr] + kk)], &As[lseg[rr]]);
#pragma unroll
        for (int rr = 0; rr < 4; ++rr)
            gll16(&BT[(size_t)(offB[rr] + kk)], &Bs[lseg[rr]]);
        __syncthreads();

#pragma unroll
        for (int ks = 0; ks < 2; ++ks) {
            short8 af[4], bfr[4];
#pragma unroll
            for (int i = 0; i < 4; ++i)
                af[i] = *(const short8*)&As[(wm * 64 + i * 16 + ln) * 64 +
                                            ((ks * 4 + quad) ^ (ln & 7)) * 8];
#pragma unroll
            for (int j = 0; j < 4; ++j)
                bfr[j] = *(const short8*)&Bs[(wn * 64 + j * 16 + ln) * 64 +
                                             ((ks * 4 + quad) ^ (ln & 7)) * 8];
#pragma unroll
            for (int i = 0; i < 4; ++i)
#pragma unroll
                for (int j = 0; j < 4; ++j)
                    acc[i][j] = MFMA16(af[i], bfr[j], acc[i][j]);
        }
    }

#pragma unroll
    for (int j = 0; j < 4; ++j) {
        int n = n0 + wn * 64 + j * 16 + ln;
        float bv = bias[n];
#pragma unroll
        for (int i = 0; i < 4; ++i) {
            int mb = m0 + wm * 64 + i * 16 + quad * 4;
#pragma unroll
            for (int r = 0; r < 4; ++r)
                Out[(size_t)(mb + r) * 1024 + n] = acc[i][j][r] + bv;
        }
    }
}

// ---------------------------------------------------------------------------
// Flash attention v9 (unchanged from R6; ~<82us after cvt_pk fix).
// 256 thr / 4 waves, 32 q-rows/wave, KVBLK=64 double-buffered, one barrier
// per tile, XCD-swizzled grid, setprio around MFMA clusters.
// ---------------------------------------------------------------------------
__global__ __launch_bounds__(256, 4) void attn_kernel(
    const ushort* __restrict__ Qw, const ushort* __restrict__ Kw,
    const ushort* __restrict__ Vtw, ushort* __restrict__ attn)
{
    __shared__ ushort Ks[2][4096];      // 64 kv x 64 d, XOR chunk swizzle
    __shared__ ushort Vts[2][4096];     // 64 d  x 64 kv, XOR chunk swizzle

    const int tid = threadIdx.x;
    const int w = tid >> 6, lane = tid & 63;
    const int ln = tid & 15, quad = (tid >> 4) & 3;
    // XCD swizzle (bijective over 1024 = 8*128): xcd = id&7 = bh&7.
    const int id = blockIdx.x;
    const int qt = (id >> 3) & 15;
    const int bh = (id & 7) | ((id >> 7) << 3);
    const int b = bh >> 4, h = bh & 15;

    const ushort* Qg = Qw + (size_t)bh * 131072 + (size_t)qt * 8192;
    const ushort* Kg = Kw + (size_t)bh * 131072;
    const ushort* Vg = Vtw + (size_t)bh * 131072;

    // Q fragments (B-operand of K=32 QK): lane holds Q[q=w*32+qs*16+ln][d]
    short8 bq[2][2];
#pragma unroll
    for (int qs = 0; qs < 2; ++qs)
#pragma unroll
        for (int ks = 0; ks < 2; ++ks)
            bq[qs][ks] = *(const short8*)&Qg[(w * 32 + qs * 16 + ln) * 64 + ks * 32 + quad * 8];

    int offK[2], offV[2], lseg[2];
#pragma unroll
    for (int rr = 0; rr < 2; ++rr) {
        int idx = (rr * 4 + w) * 64 + lane;
        int r = idx >> 3, cst = idx & 7, csrc = cst ^ (r & 7);
        offK[rr] = r * 64 + csrc * 8;
        offV[rr] = r * 2048 + csrc * 8;
        lseg[rr] = (rr * 4 + w) * 512;
    }

    const short8 ones8 = {(short)0x3F80, (short)0x3F80, (short)0x3F80, (short)0x3F80,
                          (short)0x3F80, (short)0x3F80, (short)0x3F80, (short)0x3F80};

    f32x4 Of[2][4] = {};     // O^T: col = q = ln (qs slab), rows = d-local quad*4+r
    f32x4 lac[2] = {};       // col-sums of P: col = q = ln, rows all equal

    // prologue: stage tile 0 into buffer 0 (drained by the barrier below)
#pragma unroll
    for (int rr = 0; rr < 2; ++rr) gll16(&Kg[offK[rr]], &Ks[0][lseg[rr]]);
#pragma unroll
    for (int rr = 0; rr < 2; ++rr) gll16(&Vg[offV[rr]], &Vts[0][lseg[rr]]);
    __syncthreads();

    auto body = [&](int kt, const ushort* Kc, const ushort* Vc,
                    ushort* Kn, ushort* Vn) {
        // issue next tile's async global->LDS loads FIRST; the end-of-body
        // barrier's vmcnt(0) drain then overlaps this tile's compute.
        if (kt < 31) {
#pragma unroll
            for (int rr = 0; rr < 2; ++rr)
                gll16(&Kg[(kt + 1) * 4096 + offK[rr]], &Kn[lseg[rr]]);
#pragma unroll
            for (int rr = 0; rr < 2; ++rr)
                gll16(&Vg[(kt + 1) * 64 + offV[rr]], &Vn[lseg[rr]]);
        }

#pragma unroll
        for (int c = 0; c < 2; ++c) {
            // batch K fragment reads, then a pure-MFMA QK cluster
            short8 a0[2], a1[2];
#pragma unroll
            for (int kb = 0; kb < 2; ++kb) {
                int kv = 2 * c + kb;
                a0[kb] = *(const short8*)&Kc[(kv * 16 + ln) * 64 + (quad ^ (ln & 7)) * 8];
                a1[kb] = *(const short8*)&Kc[(kv * 16 + ln) * 64 + ((4 + quad) ^ (ln & 7)) * 8];
            }
            f32x4 s[2][2];
            __builtin_amdgcn_s_setprio(1);
#pragma unroll
            for (int kb = 0; kb < 2; ++kb)
#pragma unroll
                for (int qs = 0; qs < 2; ++qs) {
                    f32x4 t = {};
                    t = MFMA16(a0[kb], bq[qs][0], t);
                    t = MFMA16(a1[kb], bq[qs][1], t);
                    s[kb][qs] = t;
                }
            __builtin_amdgcn_s_setprio(0);

            // exp2 + hardware pack into CONCATENATED K=32 B-operand
            short8 pf8[2];
#pragma unroll
            for (int qs = 0; qs < 2; ++qs) {
                pk8_u pu;
                pu.u4[0] = pk_bf16(__builtin_amdgcn_exp2f(s[0][qs][0]),
                                   __builtin_amdgcn_exp2f(s[0][qs][1]));
                pu.u4[1] = pk_bf16(__builtin_amdgcn_exp2f(s[0][qs][2]),
                                   __builtin_amdgcn_exp2f(s[0][qs][3]));
                pu.u4[2] = pk_bf16(__builtin_amdgcn_exp2f(s[1][qs][0]),
                                   __builtin_amdgcn_exp2f(s[1][qs][1]));
                pu.u4[3] = pk_bf16(__builtin_amdgcn_exp2f(s[1][qs][2]),
                                   __builtin_amdgcn_exp2f(s[1][qs][3]));
                pf8[qs] = pu.s8;
                lac[qs] = MFMA16(ones8, pu.s8, lac[qs]);   // denominator, K=32
            }

            // batch V fragment reads, then a pure-MFMA PV cluster
            cat8_u av[4];
#pragma unroll
            for (int ds = 0; ds < 4; ++ds) {
                const ushort* vrow = &Vc[(ds * 16 + ln) * 64];
                av[ds].s4[0] = *(const short4_t*)&vrow[(((4 * c + (quad >> 1)) ^ (ln & 7)) * 8) + (quad & 1) * 4];
                av[ds].s4[1] = *(const short4_t*)&vrow[(((4 * c + 2 + (quad >> 1)) ^ (ln & 7)) * 8) + (quad & 1) * 4];
            }
            __builtin_amdgcn_s_setprio(1);
#pragma unroll
            for (int ds = 0; ds < 4; ++ds)
#pragma unroll
                for (int qs = 0; qs < 2; ++qs)
                    Of[qs][ds] = MFMA16(av[ds].s8, pf8[qs], Of[qs][ds]);
            __builtin_amdgcn_s_setprio(0);
        }

        // single barrier per tile: drains next-tile vmcnt (overlapped with the
        // compute above) AND guarantees all waves finished reading this buffer.
        __syncthreads();
    };

    for (int kt = 0; kt < 32; kt += 2) {
        body(kt,     Ks[0], Vts[0], Ks[1], Vts[1]);
        body(kt + 1, Ks[1], Vts[1], Ks[0], Vts[0]);
    }

    // finalize: lane ln owns q = w*32 + qs*16 + ln for both l and O columns
#pragma unroll
    for (int qs = 0; qs < 2; ++qs) {
        float inv = __builtin_amdgcn_rcpf(lac[qs][0]);
        int t = qt * 128 + w * 32 + qs * 16 + ln;
        size_t base = ((size_t)(b * 2048 + t) << 10) + h * 64;
#pragma unroll
        for (int ds = 0; ds < 4; ++ds) {
            uint2 o;
            o.x = pk_bf16(Of[qs][ds][0] * inv, Of[qs][ds][1] * inv);
            o.y = pk_bf16(Of[qs][ds][2] * inv, Of[qs][ds][3] * inv);
            *(uint2*)&attn[base + ds * 16 + quad * 4] = o;
        }
    }
}

// ---------------------------------------------------------------------------
extern "C" void kernel_launch(void* const* d_in, const int* in_sizes, int n_in,
                              void* d_out, int out_size, void* d_ws, size_t ws_size,
                              hipStream_t stream)
{
    const float* query   = (const float*)d_in[0];
    const float* context = (const float*)d_in[1];
    const float* Wq = (const float*)d_in[2];
    const float* bq = (const float*)d_in[3];
    const float* Wk = (const float*)d_in[4];
    const float* bk = (const float*)d_in[5];
    const float* Wv = (const float*)d_in[6];
    const float* bv = (const float*)d_in[7];
    const float* Wo = (const float*)d_in[8];
    const float* bo = (const float*)d_in[9];

    char* ws = (char*)d_ws;
    ushort* WT  = (ushort*)ws;                        // 4 x 2 MB bf16 [n][k]
    ushort* Qb  = (ushort*)(ws + 8388608);            // query bf16; later Aw
    ushort* Qw  = (ushort*)(ws + 25165824);           // [b,h,t,d] (pre-scaled)
    ushort* Kw  = (ushort*)(ws + 41943040);           // [b,h,t,d]
    ushort* Vtw = (ushort*)(ws + 58720256);           // [b,h,d,t]
    ushort* Aw  = Qb;                                 // attn out reuses Qb
    ushort* Cb  = (ushort*)d_out;                     // context bf16 in d_out

    const float SCALE = 0.18033688011112042f;         // log2(e)/sqrt(64)

    cvt_all_kernel<<<dim3(9216), 256, 0, stream>>>(query, context, Qb, Cb,
                                                   Wq, Wk, Wv, Wo, WT);
    proj_kernel<<<dim3(1536), 256, 0, stream>>>(Qb, Cb, WT, bq, bk, bv,
                                                Qw, Kw, Vtw, SCALE);
    attn_kernel<<<dim3(1024), 256, 0, stream>>>(Qw, Kw, Vtw, Aw);
    gemm_o_kernel<<<dim3(512), 256, 0, stream>>>(Aw, WT + 3 * 1048576, bo,
                                                 (float*)d_out);
}